// Round 1
// 354.149 us; speedup vs baseline: 1.0752x; 1.0752x over previous
//
#include <hip/hip_runtime.h>
#include <hip/hip_bf16.h>
#include <hip/hip_fp16.h>

#define N_NODES 100000
#define DFEAT 128
#define SLAB 4096         // edges per partition block
#define BSHIFT 9          // 512 nodes per bucket
#define NBUCK 196         // ceil(100000/512)

// ---------------- ws layout (4-byte units) ----------------
// cnt    [0      , 100000)   written by phase3 (no memset needed)
// gh     [100000 , 176636)   bucket-major (bucket,block) histogram -> scanned bases
// partialB[180000, 180512)
// offs   [200000 , 300096)   written by phase3
// esrc   [300608 , 1900608)
// aggh   [1900608, 8300608)   first: int2 pairs buffer; then fp16 agg1 / h
// casth  [8300608, 14700608)  fp16 x_h, then agg2
#define WS_CNT      0
#define WS_GH       100000
#define WS_PARTB    180000
#define WS_OFFS     200000
#define WS_ESRC     300608
#define WS_AGGH     1900608
#define WS_CASTH    8300608

typedef _Float16 half8 __attribute__((ext_vector_type(8)));
typedef _Float16 half2v __attribute__((ext_vector_type(2)));
typedef float floatx4 __attribute__((ext_vector_type(4)));

// ---------- fused prep: cast x->fp16 (blocks < castblocks) + slab bucket hist ----------
// NO global atomics: per-node degree is derived later in phase3.
__global__ __launch_bounds__(256) void prep_kernel(const float* __restrict__ x,
                                                   __half* __restrict__ xh, int total4,
                                                   const int* __restrict__ dst,
                                                   int* __restrict__ gh,
                                                   int E, int bpart, int castblocks) {
    __shared__ int lh[NBUCK];
    int b = blockIdx.x;
    if (b < castblocks) {
        int i = b * 256 + threadIdx.x;
        if (i < total4) {
            float4 v = ((const float4*)x)[i];
            __half2 h01 = __floats2half2_rn(v.x, v.y);
            __half2 h23 = __floats2half2_rn(v.z, v.w);
            uint2 o;
            o.x = *(unsigned int*)&h01;
            o.y = *(unsigned int*)&h23;
            ((uint2*)xh)[i] = o;
        }
        return;
    }
    int bb = b - castblocks;
    for (int i = threadIdx.x; i < NBUCK; i += 256) lh[i] = 0;
    __syncthreads();
    int s0 = bb * SLAB, s1 = min(E, s0 + SLAB);
    for (int i = s0 + threadIdx.x; i < s1; i += 256)
        atomicAdd(&lh[dst[i] >> BSHIFT], 1);
    __syncthreads();
    for (int i = threadIdx.x; i < NBUCK; i += 256) gh[i * bpart + bb] = lh[i];
}

// ---------- exclusive-scan trio over gh (in-place) ----------
__global__ void scan1_kernel(int* __restrict__ gh, int* __restrict__ partial, int m) {
    __shared__ int s[256];
    int i = blockIdx.x * 256 + threadIdx.x;
    int v = (i < m) ? gh[i] : 0;
    s[threadIdx.x] = v;
    __syncthreads();
    for (int d = 1; d < 256; d <<= 1) {
        int t = (threadIdx.x >= d) ? s[threadIdx.x - d] : 0;
        __syncthreads();
        s[threadIdx.x] += t;
        __syncthreads();
    }
    int incl = s[threadIdx.x];
    if (i < m) gh[i] = incl - v;
    if (threadIdx.x == 255) partial[blockIdx.x] = incl;
}

__global__ void scan2_kernel(int* __restrict__ partial, int nb) {
    __shared__ int s[512];
    int t = threadIdx.x;
    int v = (t < nb) ? partial[t] : 0;
    s[t] = v;
    __syncthreads();
    for (int d = 1; d < 512; d <<= 1) {
        int u = (t >= d) ? s[t - d] : 0;
        __syncthreads();
        s[t] += u;
        __syncthreads();
    }
    if (t < nb) partial[t] = s[t] - v;
}

__global__ void scan3_kernel(int* __restrict__ gh, const int* __restrict__ partial, int m) {
    int i = blockIdx.x * 256 + threadIdx.x;
    if (i < m) gh[i] += partial[blockIdx.x];
}

// ---------- phase 2: LDS counting-sort slab by bucket, copy runs out ----------
__global__ __launch_bounds__(256) void phase2_kernel(const int* __restrict__ src,
                                                     const int* __restrict__ dst,
                                                     const int* __restrict__ gbase,
                                                     int2* __restrict__ pairs,
                                                     int E, int bpart) {
    __shared__ int lbase[NBUCK];
    __shared__ int lcur[NBUCK];
    __shared__ int lgb[NBUCK];
    __shared__ int sc[256];
    __shared__ int2 lp[SLAB];   // 32 KB
    int b = blockIdx.x;
    int t = threadIdx.x;
    for (int i = t; i < NBUCK; i += 256) lbase[i] = 0;
    __syncthreads();
    int s0 = b * SLAB, s1 = min(E, s0 + SLAB);
    for (int i = s0 + t; i < s1; i += 256)
        atomicAdd(&lbase[dst[i] >> BSHIFT], 1);
    __syncthreads();
    int v = (t < NBUCK) ? lbase[t] : 0;
    sc[t] = v;
    __syncthreads();
    for (int d = 1; d < 256; d <<= 1) {
        int u = (t >= d) ? sc[t - d] : 0;
        __syncthreads();
        sc[t] += u;
        __syncthreads();
    }
    if (t < NBUCK) {
        int excl = sc[t] - v;
        lbase[t] = excl;
        lcur[t] = excl;
        lgb[t] = gbase[t * bpart + b];
    }
    __syncthreads();
    for (int i = s0 + t; i < s1; i += 256) {
        int d = dst[i];
        int s = src[i];
        int bk = d >> BSHIFT;
        int pos = atomicAdd(&lcur[bk], 1);
        lp[pos] = make_int2(s, d);
    }
    __syncthreads();
    int m = s1 - s0;
    for (int i = t; i < m; i += 256) {
        int2 p = lp[i];
        int bk = p.y >> BSHIFT;
        pairs[lgb[bk] + (i - lbase[bk])] = p;
    }
}

// ---------- phase 3: per-bucket node hist (LDS) + scan -> cnt/offs + CSR finalize ----------
__global__ __launch_bounds__(512) void phase3_kernel(const int2* __restrict__ pairs,
                                                     const int* __restrict__ gbase,
                                                     int* __restrict__ cnt,
                                                     int* __restrict__ offs,
                                                     int* __restrict__ esrc,
                                                     int E, int bpart, int n) {
    __shared__ int lcnt[512];
    __shared__ int sc[512];
    __shared__ int lexcl[512];
    int g = blockIdx.x;
    int node0 = g << BSHIFT;
    int t = threadIdx.x;
    lcnt[t] = 0;
    __syncthreads();
    int S = gbase[g * bpart];
    int Eg = (g == NBUCK - 1) ? E : gbase[(g + 1) * bpart];
    // pass 1: count per node (LDS atomics)
    for (int i = S + t; i < Eg; i += 512)
        atomicAdd(&lcnt[pairs[i].y - node0], 1);
    __syncthreads();
    // exclusive scan of 512 counters
    int v = lcnt[t];
    sc[t] = v;
    __syncthreads();
    for (int d = 1; d < 512; d <<= 1) {
        int u = (t >= d) ? sc[t - d] : 0;
        __syncthreads();
        sc[t] += u;
        __syncthreads();
    }
    int excl = sc[t] - v;
    lexcl[t] = excl;
    int nd = node0 + t;
    if (nd < n) {
        cnt[nd] = v;
        offs[nd] = S + excl;
    }
    __syncthreads();
    // pass 2: place edges; lexcl doubles as cursor (old value = slot in bucket)
    for (int i = S + t; i < Eg; i += 512) {
        int2 p = pairs[i];
        int pos = atomicAdd(&lexcl[p.y - node0], 1);
        esrc[S + pos] = p.x;
    }
}

// ---------- aggregate: one wave per node, 4 edges/step x 16 lanes x 16B loads ----------
// Latency-bound random gather: maximize bytes-in-flight per outstanding request.
// Each lane owns 8 fp16 columns (16 B, dwordx4); lane-group (lane>>4) = edge slot.
__global__ void aggregate_kernel(const __half* __restrict__ feat, const int* __restrict__ esrc,
                                 const int* __restrict__ offs, const int* __restrict__ cnt,
                                 __half* __restrict__ agg, int n) {
    int wid = (blockIdx.x * blockDim.x + threadIdx.x) >> 6;
    int lane = threadIdx.x & 63;
    if (wid >= n) return;
    int beg = offs[wid];
    int deg = cnt[wid];
    int grp = lane >> 4;            // 0..3: edge slot within a 4-pack
    int colbase = (lane & 15) * 8;  // 8 fp16 = 16 B per lane

    half2v s0 = (half2v)(_Float16)0;
    half2v s1 = (half2v)(_Float16)0;
    half2v s2 = (half2v)(_Float16)0;
    half2v s3 = (half2v)(_Float16)0;

    for (int base = 0; base < deg; base += 64) {
        int m = min(64, deg - base);
        int idx = (lane < m) ? esrc[beg + base + lane] : 0;
#pragma unroll 4
        for (int j = 0; j < m; j += 4) {
            int jj = j + grp;
            bool valid = jj < m;
            int sidx = __shfl(idx, valid ? jj : 0);
            uint4 raw = *(const uint4*)(feat + (size_t)sidx * DFEAT + colbase);
            if (!valid) { raw.x = 0u; raw.y = 0u; raw.z = 0u; raw.w = 0u; }
            s0 += *(half2v*)&raw.x;
            s1 += *(half2v*)&raw.y;
            s2 += *(half2v*)&raw.z;
            s3 += *(half2v*)&raw.w;
        }
    }
    float a[8];
    a[0] = (float)s0.x; a[1] = (float)s0.y;
    a[2] = (float)s1.x; a[3] = (float)s1.y;
    a[4] = (float)s2.x; a[5] = (float)s2.y;
    a[6] = (float)s3.x; a[7] = (float)s3.y;
#pragma unroll
    for (int k = 0; k < 8; k++) {
        a[k] += __shfl_xor(a[k], 16);
        a[k] += __shfl_xor(a[k], 32);
    }
    if (lane < 16) {
        float scale = 1.0f / fmaxf((float)deg, 1.0f);
        __half2 h0 = __floats2half2_rn(a[0] * scale, a[1] * scale);
        __half2 h1 = __floats2half2_rn(a[2] * scale, a[3] * scale);
        __half2 h2 = __floats2half2_rn(a[4] * scale, a[5] * scale);
        __half2 h3 = __floats2half2_rn(a[6] * scale, a[7] * scale);
        uint4 o;
        o.x = *(unsigned int*)&h0;
        o.y = *(unsigned int*)&h1;
        o.z = *(unsigned int*)&h2;
        o.w = *(unsigned int*)&h3;
        *(uint4*)(agg + (size_t)wid * DFEAT + colbase) = o;
    }
}

// ---------- MFMA dual-GEMM, LDS-staged weights, D[feat][node] orientation ----------
template <bool NORM_RELU>
__global__ __launch_bounds__(256) void gemm_mfma_kernel(
    const __half* __restrict__ A1_, const __half* __restrict__ A2_,
    const float* __restrict__ Wl, const float* __restrict__ Wr,
    const float* __restrict__ bias, float* __restrict__ out32,
    __half* __restrict__ out16, int n) {
    __shared__ __align__(16) _Float16 lw[128 * 136];   // 34.8 KB

    const _Float16* A1 = (const _Float16*)A1_;
    const _Float16* A2 = (const _Float16*)A2_;

    const int lane = threadIdx.x & 63;
    const int w = threadIdx.x >> 6;       // wave 0..3
    const int quad = lane >> 4;           // 0..3
    const int l15 = lane & 15;
    const int i0 = blockIdx.x * 128 + w * 32;   // wave's first node row

    floatx4 acc[2][8];
#pragma unroll
    for (int nt = 0; nt < 2; nt++)
#pragma unroll
        for (int ft = 0; ft < 8; ft++)
            acc[nt][ft] = (floatx4){0.f, 0.f, 0.f, 0.f};

    int r0 = i0 + l15;      if (r0 >= n) r0 = n - 1;
    int r1 = i0 + 16 + l15; if (r1 >= n) r1 = n - 1;
    const int kq = quad * 8;

    for (int half = 0; half < 2; half++) {
        const float* __restrict__ W = half ? Wr : Wl;
        const _Float16* __restrict__ A = half ? A2 : A1;
        if (half) __syncthreads();
        {
            int t = threadIdx.x;
            int row = t >> 1;
            int cb = (t & 1) * 64;
            const float4* sp = (const float4*)(W + row * DFEAT + cb);
            unsigned int* dp = (unsigned int*)&lw[row * 136 + cb];
#pragma unroll
            for (int q = 0; q < 16; q++) {
                float4 v = sp[q];
                __half2 h01 = __floats2half2_rn(v.x, v.y);
                __half2 h23 = __floats2half2_rn(v.z, v.w);
                dp[q * 2] = *(unsigned int*)&h01;
                dp[q * 2 + 1] = *(unsigned int*)&h23;
            }
        }
        __syncthreads();
#pragma unroll
        for (int kc = 0; kc < DFEAT; kc += 32) {
            half8 b0 = *(const half8*)(A + (size_t)r0 * DFEAT + kc + kq);
            half8 b1 = *(const half8*)(A + (size_t)r1 * DFEAT + kc + kq);
#pragma unroll
            for (int ft = 0; ft < 8; ft++) {
                half8 a = *(const half8*)&lw[(ft * 16 + l15) * 136 + kc + kq];
                acc[0][ft] = __builtin_amdgcn_mfma_f32_16x16x32_f16(a, b0, acc[0][ft], 0, 0, 0);
                acc[1][ft] = __builtin_amdgcn_mfma_f32_16x16x32_f16(a, b1, acc[1][ft], 0, 0, 0);
            }
        }
    }

#pragma unroll
    for (int nt = 0; nt < 2; nt++) {
        int node = i0 + nt * 16 + l15;
        float v[8][4];
#pragma unroll
        for (int ft = 0; ft < 8; ft++) {
            const float4 bq = *(const float4*)(bias + ft * 16 + quad * 4);
            v[ft][0] = acc[nt][ft][0] + bq.x;
            v[ft][1] = acc[nt][ft][1] + bq.y;
            v[ft][2] = acc[nt][ft][2] + bq.z;
            v[ft][3] = acc[nt][ft][3] + bq.w;
        }
        if (NORM_RELU) {
            float ss = 0.f;
#pragma unroll
            for (int ft = 0; ft < 8; ft++)
#pragma unroll
                for (int r = 0; r < 4; r++) ss = fmaf(v[ft][r], v[ft][r], ss);
            ss += __shfl_xor(ss, 16);
            ss += __shfl_xor(ss, 32);
            float inv = 1.0f / fmaxf(sqrtf(ss), 1e-12f);
#pragma unroll
            for (int ft = 0; ft < 8; ft++)
#pragma unroll
                for (int r = 0; r < 4; r++) v[ft][r] = fmaxf(v[ft][r] * inv, 0.0f);
        }
        if (node < n) {
            if (NORM_RELU) {
                __half* op = (__half*)out16 + (size_t)node * DFEAT + quad * 4;
#pragma unroll
                for (int ft = 0; ft < 8; ft++) {
                    __half2 h01 = __floats2half2_rn(v[ft][0], v[ft][1]);
                    __half2 h23 = __floats2half2_rn(v[ft][2], v[ft][3]);
                    uint2 o;
                    o.x = *(unsigned int*)&h01;
                    o.y = *(unsigned int*)&h23;
                    *(uint2*)(op + ft * 16) = o;
                }
            } else {
                float* op = out32 + (size_t)node * DFEAT + quad * 4;
#pragma unroll
                for (int ft = 0; ft < 8; ft++)
                    *(float4*)(op + ft * 16) = make_float4(v[ft][0], v[ft][1], v[ft][2], v[ft][3]);
            }
        }
    }
}

extern "C" void kernel_launch(void* const* d_in, const int* in_sizes, int n_in,
                              void* d_out, int out_size, void* d_ws, size_t ws_size,
                              hipStream_t stream) {
    const float* x = (const float*)d_in[0];
    const int* edge_index = (const int*)d_in[1];
    const float* W1l = (const float*)d_in[2];
    const float* b1 = (const float*)d_in[3];
    const float* W1r = (const float*)d_in[4];
    const float* W2l = (const float*)d_in[5];
    const float* b2 = (const float*)d_in[6];
    const float* W2r = (const float*)d_in[7];
    float* out = (float*)d_out;

    const int E = in_sizes[1] / 2;
    const int n = in_sizes[0] / DFEAT;  // 100000

    int* ws = (int*)d_ws;
    int* cnt = ws + WS_CNT;
    int* gh = ws + WS_GH;
    int* partialB = ws + WS_PARTB;
    int* offs = ws + WS_OFFS;
    int* esrc = ws + WS_ESRC;
    int2* pairs = (int2*)(ws + WS_AGGH);
    __half* aggh = (__half*)(ws + WS_AGGH);
    __half* casth = (__half*)(ws + WS_CASTH);

    const int* src = edge_index;
    const int* dst = edge_index + E;

    const int bpart = (E + SLAB - 1) / SLAB;        // 391
    const int m = NBUCK * bpart;                    // 76636
    const int blocksB = (m + 255) / 256;            // 300
    const int total4 = n * DFEAT / 4;
    const int castblocks = (total4 + 255) / 256;    // 12500

    prep_kernel<<<castblocks + bpart, 256, 0, stream>>>(x, casth, total4, dst, gh,
                                                        E, bpart, castblocks);
    scan1_kernel<<<blocksB, 256, 0, stream>>>(gh, partialB, m);
    scan2_kernel<<<1, 512, 0, stream>>>(partialB, blocksB);
    scan3_kernel<<<blocksB, 256, 0, stream>>>(gh, partialB, m);

    phase2_kernel<<<bpart, 256, 0, stream>>>(src, dst, gh, pairs, E, bpart);
    phase3_kernel<<<NBUCK, 512, 0, stream>>>(pairs, gh, cnt, offs, esrc, E, bpart, n);

    const int aggb = (n * 64 + 255) / 256;
    const int gemmb = (n + 127) / 128;

    // layer 1: agg(x_h) -> aggh; h = relu(normalize(aggh@W1l^T + b1 + x_h@W1r^T)) -> fp16 aggh
    aggregate_kernel<<<aggb, 256, 0, stream>>>(casth, esrc, offs, cnt, aggh, n);
    gemm_mfma_kernel<true><<<gemmb, 256, 0, stream>>>(aggh, casth, W1l, W1r, b1, nullptr, aggh, n);

    // layer 2: agg(h) -> casth; out = casth@W2l^T + b2 + h@W2r^T (fp32 to d_out)
    aggregate_kernel<<<aggb, 256, 0, stream>>>(aggh, esrc, offs, cnt, casth, n);
    gemm_mfma_kernel<false><<<gemmb, 256, 0, stream>>>(casth, aggh, W2l, W2r, b2, out, nullptr, n);
}

// Round 2
// 348.339 us; speedup vs baseline: 1.0931x; 1.0167x over previous
//
#include <hip/hip_runtime.h>
#include <hip/hip_bf16.h>
#include <hip/hip_fp16.h>

#define N_NODES 100000
#define DFEAT 128
#define SLAB 4096         // edges per partition block
#define BSHIFT 9          // 512 nodes per bucket
#define NBUCK 196         // ceil(100000/512)

// ---------------- ws layout (4-byte units) ----------------
// cnt    [0      , 100000)   written by phase3 (no memset needed)
// gh     [100000 , 176636)   bucket-major (bucket,block) histogram -> scanned bases
// partialB[180000, 180512)
// offs   [200000 , 300096)   written by phase3
// esrc   [300608 , 1900608)
// aggh   [1900608, 8300608)   first: int2 pairs buffer; then fp16 agg1 / h
// casth  [8300608, 14700608)  fp16 x_h, then agg2
#define WS_CNT      0
#define WS_GH       100000
#define WS_PARTB    180000
#define WS_OFFS     200000
#define WS_ESRC     300608
#define WS_AGGH     1900608
#define WS_CASTH    8300608

typedef _Float16 half8 __attribute__((ext_vector_type(8)));
typedef _Float16 half2v __attribute__((ext_vector_type(2)));
typedef float floatx4 __attribute__((ext_vector_type(4)));

// ---------- fused prep: cast x->fp16 (blocks < castblocks) + slab bucket hist ----------
// NO global atomics: per-node degree is derived later in phase3.
__global__ __launch_bounds__(256) void prep_kernel(const float* __restrict__ x,
                                                   __half* __restrict__ xh, int total4,
                                                   const int* __restrict__ dst,
                                                   int* __restrict__ gh,
                                                   int E, int bpart, int castblocks) {
    __shared__ int lh[NBUCK];
    int b = blockIdx.x;
    if (b < castblocks) {
        int i = b * 256 + threadIdx.x;
        if (i < total4) {
            float4 v = ((const float4*)x)[i];
            __half2 h01 = __floats2half2_rn(v.x, v.y);
            __half2 h23 = __floats2half2_rn(v.z, v.w);
            uint2 o;
            o.x = *(unsigned int*)&h01;
            o.y = *(unsigned int*)&h23;
            ((uint2*)xh)[i] = o;
        }
        return;
    }
    int bb = b - castblocks;
    for (int i = threadIdx.x; i < NBUCK; i += 256) lh[i] = 0;
    __syncthreads();
    int s0 = bb * SLAB, s1 = min(E, s0 + SLAB);
    for (int i = s0 + threadIdx.x; i < s1; i += 256)
        atomicAdd(&lh[dst[i] >> BSHIFT], 1);
    __syncthreads();
    for (int i = threadIdx.x; i < NBUCK; i += 256) gh[i * bpart + bb] = lh[i];
}

// ---------- exclusive-scan trio over gh (in-place) ----------
__global__ void scan1_kernel(int* __restrict__ gh, int* __restrict__ partial, int m) {
    __shared__ int s[256];
    int i = blockIdx.x * 256 + threadIdx.x;
    int v = (i < m) ? gh[i] : 0;
    s[threadIdx.x] = v;
    __syncthreads();
    for (int d = 1; d < 256; d <<= 1) {
        int t = (threadIdx.x >= d) ? s[threadIdx.x - d] : 0;
        __syncthreads();
        s[threadIdx.x] += t;
        __syncthreads();
    }
    int incl = s[threadIdx.x];
    if (i < m) gh[i] = incl - v;
    if (threadIdx.x == 255) partial[blockIdx.x] = incl;
}

__global__ void scan2_kernel(int* __restrict__ partial, int nb) {
    __shared__ int s[512];
    int t = threadIdx.x;
    int v = (t < nb) ? partial[t] : 0;
    s[t] = v;
    __syncthreads();
    for (int d = 1; d < 512; d <<= 1) {
        int u = (t >= d) ? s[t - d] : 0;
        __syncthreads();
        s[t] += u;
        __syncthreads();
    }
    if (t < nb) partial[t] = s[t] - v;
}

__global__ void scan3_kernel(int* __restrict__ gh, const int* __restrict__ partial, int m) {
    int i = blockIdx.x * 256 + threadIdx.x;
    if (i < m) gh[i] += partial[blockIdx.x];
}

// ---------- phase 2: LDS counting-sort slab by bucket, copy runs out ----------
__global__ __launch_bounds__(256) void phase2_kernel(const int* __restrict__ src,
                                                     const int* __restrict__ dst,
                                                     const int* __restrict__ gbase,
                                                     int2* __restrict__ pairs,
                                                     int E, int bpart) {
    __shared__ int lbase[NBUCK];
    __shared__ int lcur[NBUCK];
    __shared__ int lgb[NBUCK];
    __shared__ int sc[256];
    __shared__ int2 lp[SLAB];   // 32 KB
    int b = blockIdx.x;
    int t = threadIdx.x;
    for (int i = t; i < NBUCK; i += 256) lbase[i] = 0;
    __syncthreads();
    int s0 = b * SLAB, s1 = min(E, s0 + SLAB);
    for (int i = s0 + t; i < s1; i += 256)
        atomicAdd(&lbase[dst[i] >> BSHIFT], 1);
    __syncthreads();
    int v = (t < NBUCK) ? lbase[t] : 0;
    sc[t] = v;
    __syncthreads();
    for (int d = 1; d < 256; d <<= 1) {
        int u = (t >= d) ? sc[t - d] : 0;
        __syncthreads();
        sc[t] += u;
        __syncthreads();
    }
    if (t < NBUCK) {
        int excl = sc[t] - v;
        lbase[t] = excl;
        lcur[t] = excl;
        lgb[t] = gbase[t * bpart + b];
    }
    __syncthreads();
    for (int i = s0 + t; i < s1; i += 256) {
        int d = dst[i];
        int s = src[i];
        int bk = d >> BSHIFT;
        int pos = atomicAdd(&lcur[bk], 1);
        lp[pos] = make_int2(s, d);
    }
    __syncthreads();
    int m = s1 - s0;
    for (int i = t; i < m; i += 256) {
        int2 p = lp[i];
        int bk = p.y >> BSHIFT;
        pairs[lgb[bk] + (i - lbase[bk])] = p;
    }
}

// ---------- phase 3: per-bucket node hist (LDS) + scan -> cnt/offs + CSR finalize ----------
__global__ __launch_bounds__(512) void phase3_kernel(const int2* __restrict__ pairs,
                                                     const int* __restrict__ gbase,
                                                     int* __restrict__ cnt,
                                                     int* __restrict__ offs,
                                                     int* __restrict__ esrc,
                                                     int E, int bpart, int n) {
    __shared__ int lcnt[512];
    __shared__ int sc[512];
    __shared__ int lexcl[512];
    int g = blockIdx.x;
    int node0 = g << BSHIFT;
    int t = threadIdx.x;
    lcnt[t] = 0;
    __syncthreads();
    int S = gbase[g * bpart];
    int Eg = (g == NBUCK - 1) ? E : gbase[(g + 1) * bpart];
    // pass 1: count per node (LDS atomics)
    for (int i = S + t; i < Eg; i += 512)
        atomicAdd(&lcnt[pairs[i].y - node0], 1);
    __syncthreads();
    // exclusive scan of 512 counters
    int v = lcnt[t];
    sc[t] = v;
    __syncthreads();
    for (int d = 1; d < 512; d <<= 1) {
        int u = (t >= d) ? sc[t - d] : 0;
        __syncthreads();
        sc[t] += u;
        __syncthreads();
    }
    int excl = sc[t] - v;
    lexcl[t] = excl;
    int nd = node0 + t;
    if (nd < n) {
        cnt[nd] = v;
        offs[nd] = S + excl;
    }
    __syncthreads();
    // pass 2: place edges; lexcl doubles as cursor (old value = slot in bucket)
    for (int i = S + t; i < Eg; i += 512) {
        int2 p = pairs[i];
        int pos = atomicAdd(&lexcl[p.y - node0], 1);
        esrc[S + pos] = p.x;
    }
}

// ---------- aggregate: one wave per node; 16 edges/step, 4 independent load+acc chains ----
// Latency/concurrency-bound random gather. Key: keep 4 dwordx4 loads in flight per wave
// (separate load phase + 4 independent accumulator chains so regalloc can't serialize them).
// lane layout: 16 lanes x 16B cover one 256B feature row; grp = lane>>4 picks the edge slot.
__global__ void aggregate_kernel(const __half* __restrict__ feat, const int* __restrict__ esrc,
                                 const int* __restrict__ offs, const int* __restrict__ cnt,
                                 __half* __restrict__ agg, int n) {
    int wid = (blockIdx.x * blockDim.x + threadIdx.x) >> 6;
    int lane = threadIdx.x & 63;
    if (wid >= n) return;
    int beg = offs[wid];
    int deg = cnt[wid];
    int grp = lane >> 4;            // 0..3: edge slot within a 4-pack
    int colbase = (lane & 15) * 8;  // 8 fp16 = 16 B per lane
    const _Float16* fbase = (const _Float16*)feat + colbase;

    // 4 independent fp16 accumulator chains (4 x half2v = 8 halves each)
    half2v s[4][4];
#pragma unroll
    for (int c = 0; c < 4; c++)
#pragma unroll
        for (int k = 0; k < 4; k++) s[c][k] = (half2v)(_Float16)0;

    for (int base = 0; base < deg; base += 64) {
        int m = min(64, deg - base);
        int idx = (lane < m) ? esrc[beg + base + lane] : 0;
        int j = 0;
        // main path: 16 edges/iter, 4 loads in flight, no masking
        for (; j + 16 <= m; j += 16) {
            int is[4];
#pragma unroll
            for (int c = 0; c < 4; c++) is[c] = __shfl(idx, j + 4 * c + grp);
            uint4 r[4];
#pragma unroll
            for (int c = 0; c < 4; c++)
                r[c] = *(const uint4*)(fbase + (size_t)is[c] * DFEAT);
#pragma unroll
            for (int c = 0; c < 4; c++) {
                s[c][0] += *(half2v*)&r[c].x;
                s[c][1] += *(half2v*)&r[c].y;
                s[c][2] += *(half2v*)&r[c].z;
                s[c][3] += *(half2v*)&r[c].w;
            }
        }
        // 8 edges/iter, 2 loads in flight, no masking
        for (; j + 8 <= m; j += 8) {
            int i0 = __shfl(idx, j + grp);
            int i1 = __shfl(idx, j + 4 + grp);
            uint4 r0 = *(const uint4*)(fbase + (size_t)i0 * DFEAT);
            uint4 r1 = *(const uint4*)(fbase + (size_t)i1 * DFEAT);
            s[0][0] += *(half2v*)&r0.x; s[0][1] += *(half2v*)&r0.y;
            s[0][2] += *(half2v*)&r0.z; s[0][3] += *(half2v*)&r0.w;
            s[1][0] += *(half2v*)&r1.x; s[1][1] += *(half2v*)&r1.y;
            s[1][2] += *(half2v*)&r1.z; s[1][3] += *(half2v*)&r1.w;
        }
        // masked tail: up to 4 edges
        for (; j < m; j += 4) {
            int jj = j + grp;
            bool valid = jj < m;
            int sidx = __shfl(idx, valid ? jj : 0);
            uint4 raw = *(const uint4*)(fbase + (size_t)sidx * DFEAT);
            if (!valid) { raw.x = 0u; raw.y = 0u; raw.z = 0u; raw.w = 0u; }
            s[2][0] += *(half2v*)&raw.x; s[2][1] += *(half2v*)&raw.y;
            s[2][2] += *(half2v*)&raw.z; s[2][3] += *(half2v*)&raw.w;
        }
    }

    // combine chains in fp32, then cross-group reduce (16, 32)
    float a[8];
#pragma unroll
    for (int k = 0; k < 4; k++) {
        a[2 * k]     = (float)s[0][k].x + (float)s[1][k].x + (float)s[2][k].x + (float)s[3][k].x;
        a[2 * k + 1] = (float)s[0][k].y + (float)s[1][k].y + (float)s[2][k].y + (float)s[3][k].y;
    }
#pragma unroll
    for (int k = 0; k < 8; k++) {
        a[k] += __shfl_xor(a[k], 16);
        a[k] += __shfl_xor(a[k], 32);
    }
    if (lane < 16) {
        float scale = 1.0f / fmaxf((float)deg, 1.0f);
        __half2 h0 = __floats2half2_rn(a[0] * scale, a[1] * scale);
        __half2 h1 = __floats2half2_rn(a[2] * scale, a[3] * scale);
        __half2 h2 = __floats2half2_rn(a[4] * scale, a[5] * scale);
        __half2 h3 = __floats2half2_rn(a[6] * scale, a[7] * scale);
        uint4 o;
        o.x = *(unsigned int*)&h0;
        o.y = *(unsigned int*)&h1;
        o.z = *(unsigned int*)&h2;
        o.w = *(unsigned int*)&h3;
        *(uint4*)(agg + (size_t)wid * DFEAT + colbase) = o;
    }
}

// ---------- MFMA dual-GEMM, LDS-staged weights, D[feat][node] orientation ----------
template <bool NORM_RELU>
__global__ __launch_bounds__(256) void gemm_mfma_kernel(
    const __half* __restrict__ A1_, const __half* __restrict__ A2_,
    const float* __restrict__ Wl, const float* __restrict__ Wr,
    const float* __restrict__ bias, float* __restrict__ out32,
    __half* __restrict__ out16, int n) {
    __shared__ __align__(16) _Float16 lw[128 * 136];   // 34.8 KB

    const _Float16* A1 = (const _Float16*)A1_;
    const _Float16* A2 = (const _Float16*)A2_;

    const int lane = threadIdx.x & 63;
    const int w = threadIdx.x >> 6;       // wave 0..3
    const int quad = lane >> 4;           // 0..3
    const int l15 = lane & 15;
    const int i0 = blockIdx.x * 128 + w * 32;   // wave's first node row

    floatx4 acc[2][8];
#pragma unroll
    for (int nt = 0; nt < 2; nt++)
#pragma unroll
        for (int ft = 0; ft < 8; ft++)
            acc[nt][ft] = (floatx4){0.f, 0.f, 0.f, 0.f};

    int r0 = i0 + l15;      if (r0 >= n) r0 = n - 1;
    int r1 = i0 + 16 + l15; if (r1 >= n) r1 = n - 1;
    const int kq = quad * 8;

    for (int half = 0; half < 2; half++) {
        const float* __restrict__ W = half ? Wr : Wl;
        const _Float16* __restrict__ A = half ? A2 : A1;
        if (half) __syncthreads();
        {
            int t = threadIdx.x;
            int row = t >> 1;
            int cb = (t & 1) * 64;
            const float4* sp = (const float4*)(W + row * DFEAT + cb);
            unsigned int* dp = (unsigned int*)&lw[row * 136 + cb];
#pragma unroll
            for (int q = 0; q < 16; q++) {
                float4 v = sp[q];
                __half2 h01 = __floats2half2_rn(v.x, v.y);
                __half2 h23 = __floats2half2_rn(v.z, v.w);
                dp[q * 2] = *(unsigned int*)&h01;
                dp[q * 2 + 1] = *(unsigned int*)&h23;
            }
        }
        __syncthreads();
#pragma unroll
        for (int kc = 0; kc < DFEAT; kc += 32) {
            half8 b0 = *(const half8*)(A + (size_t)r0 * DFEAT + kc + kq);
            half8 b1 = *(const half8*)(A + (size_t)r1 * DFEAT + kc + kq);
#pragma unroll
            for (int ft = 0; ft < 8; ft++) {
                half8 a = *(const half8*)&lw[(ft * 16 + l15) * 136 + kc + kq];
                acc[0][ft] = __builtin_amdgcn_mfma_f32_16x16x32_f16(a, b0, acc[0][ft], 0, 0, 0);
                acc[1][ft] = __builtin_amdgcn_mfma_f32_16x16x32_f16(a, b1, acc[1][ft], 0, 0, 0);
            }
        }
    }

#pragma unroll
    for (int nt = 0; nt < 2; nt++) {
        int node = i0 + nt * 16 + l15;
        float v[8][4];
#pragma unroll
        for (int ft = 0; ft < 8; ft++) {
            const float4 bq = *(const float4*)(bias + ft * 16 + quad * 4);
            v[ft][0] = acc[nt][ft][0] + bq.x;
            v[ft][1] = acc[nt][ft][1] + bq.y;
            v[ft][2] = acc[nt][ft][2] + bq.z;
            v[ft][3] = acc[nt][ft][3] + bq.w;
        }
        if (NORM_RELU) {
            float ss = 0.f;
#pragma unroll
            for (int ft = 0; ft < 8; ft++)
#pragma unroll
                for (int r = 0; r < 4; r++) ss = fmaf(v[ft][r], v[ft][r], ss);
            ss += __shfl_xor(ss, 16);
            ss += __shfl_xor(ss, 32);
            float inv = 1.0f / fmaxf(sqrtf(ss), 1e-12f);
#pragma unroll
            for (int ft = 0; ft < 8; ft++)
#pragma unroll
                for (int r = 0; r < 4; r++) v[ft][r] = fmaxf(v[ft][r] * inv, 0.0f);
        }
        if (node < n) {
            if (NORM_RELU) {
                __half* op = (__half*)out16 + (size_t)node * DFEAT + quad * 4;
#pragma unroll
                for (int ft = 0; ft < 8; ft++) {
                    __half2 h01 = __floats2half2_rn(v[ft][0], v[ft][1]);
                    __half2 h23 = __floats2half2_rn(v[ft][2], v[ft][3]);
                    uint2 o;
                    o.x = *(unsigned int*)&h01;
                    o.y = *(unsigned int*)&h23;
                    *(uint2*)(op + ft * 16) = o;
                }
            } else {
                float* op = out32 + (size_t)node * DFEAT + quad * 4;
#pragma unroll
                for (int ft = 0; ft < 8; ft++)
                    *(float4*)(op + ft * 16) = make_float4(v[ft][0], v[ft][1], v[ft][2], v[ft][3]);
            }
        }
    }
}

extern "C" void kernel_launch(void* const* d_in, const int* in_sizes, int n_in,
                              void* d_out, int out_size, void* d_ws, size_t ws_size,
                              hipStream_t stream) {
    const float* x = (const float*)d_in[0];
    const int* edge_index = (const int*)d_in[1];
    const float* W1l = (const float*)d_in[2];
    const float* b1 = (const float*)d_in[3];
    const float* W1r = (const float*)d_in[4];
    const float* W2l = (const float*)d_in[5];
    const float* b2 = (const float*)d_in[6];
    const float* W2r = (const float*)d_in[7];
    float* out = (float*)d_out;

    const int E = in_sizes[1] / 2;
    const int n = in_sizes[0] / DFEAT;  // 100000

    int* ws = (int*)d_ws;
    int* cnt = ws + WS_CNT;
    int* gh = ws + WS_GH;
    int* partialB = ws + WS_PARTB;
    int* offs = ws + WS_OFFS;
    int* esrc = ws + WS_ESRC;
    int2* pairs = (int2*)(ws + WS_AGGH);
    __half* aggh = (__half*)(ws + WS_AGGH);
    __half* casth = (__half*)(ws + WS_CASTH);

    const int* src = edge_index;
    const int* dst = edge_index + E;

    const int bpart = (E + SLAB - 1) / SLAB;        // 391
    const int m = NBUCK * bpart;                    // 76636
    const int blocksB = (m + 255) / 256;            // 300
    const int total4 = n * DFEAT / 4;
    const int castblocks = (total4 + 255) / 256;    // 12500

    prep_kernel<<<castblocks + bpart, 256, 0, stream>>>(x, casth, total4, dst, gh,
                                                        E, bpart, castblocks);
    scan1_kernel<<<blocksB, 256, 0, stream>>>(gh, partialB, m);
    scan2_kernel<<<1, 512, 0, stream>>>(partialB, blocksB);
    scan3_kernel<<<blocksB, 256, 0, stream>>>(gh, partialB, m);

    phase2_kernel<<<bpart, 256, 0, stream>>>(src, dst, gh, pairs, E, bpart);
    phase3_kernel<<<NBUCK, 512, 0, stream>>>(pairs, gh, cnt, offs, esrc, E, bpart, n);

    const int aggb = (n * 64 + 255) / 256;
    const int gemmb = (n + 127) / 128;

    // layer 1: agg(x_h) -> aggh; h = relu(normalize(aggh@W1l^T + b1 + x_h@W1r^T)) -> fp16 aggh
    aggregate_kernel<<<aggb, 256, 0, stream>>>(casth, esrc, offs, cnt, aggh, n);
    gemm_mfma_kernel<true><<<gemmb, 256, 0, stream>>>(aggh, casth, W1l, W1r, b1, nullptr, aggh, n);

    // layer 2: agg(h) -> casth; out = casth@W2l^T + b2 + h@W2r^T (fp32 to d_out)
    aggregate_kernel<<<aggb, 256, 0, stream>>>(aggh, esrc, offs, cnt, casth, n);
    gemm_mfma_kernel<false><<<gemmb, 256, 0, stream>>>(casth, aggh, W2l, W2r, b2, out, nullptr, n);
}

// Round 3
// 346.218 us; speedup vs baseline: 1.0998x; 1.0061x over previous
//
#include <hip/hip_runtime.h>
#include <hip/hip_bf16.h>
#include <hip/hip_fp16.h>

#define N_NODES 100000
#define DFEAT 128
#define SLAB 4096         // edges per partition block
#define BSHIFT 9          // 512 nodes per bucket
#define NBUCK 196         // ceil(100000/512)

// ---------------- ws layout (4-byte units) ----------------
// cnt    [0      , 100000)   written by phase3 (no memset needed)
// gh     [100000 , 176636)   bucket-major (bucket,block) histogram -> scanned bases
// partialB[180000, 180512)
// offs   [200000 , 300096)   written by phase3
// esrc   [300608 , 1900608)
// aggh   [1900608, 8300608)   first: int2 pairs buffer; then fp16 agg1 / h
// casth  [8300608, 14700608)  fp16 x_h, then agg2
#define WS_CNT      0
#define WS_GH       100000
#define WS_PARTB    180000
#define WS_OFFS     200000
#define WS_ESRC     300608
#define WS_AGGH     1900608
#define WS_CASTH    8300608

typedef _Float16 half8 __attribute__((ext_vector_type(8)));
typedef _Float16 half2v __attribute__((ext_vector_type(2)));
typedef float floatx4 __attribute__((ext_vector_type(4)));

// ---------- fused prep: cast x->fp16 (blocks < castblocks) + slab bucket hist ----------
// NO global atomics: per-node degree is derived later in phase3.
__global__ __launch_bounds__(256) void prep_kernel(const float* __restrict__ x,
                                                   __half* __restrict__ xh, int total4,
                                                   const int* __restrict__ dst,
                                                   int* __restrict__ gh,
                                                   int E, int bpart, int castblocks) {
    __shared__ int lh[NBUCK];
    int b = blockIdx.x;
    if (b < castblocks) {
        int i = b * 256 + threadIdx.x;
        if (i < total4) {
            float4 v = ((const float4*)x)[i];
            __half2 h01 = __floats2half2_rn(v.x, v.y);
            __half2 h23 = __floats2half2_rn(v.z, v.w);
            uint2 o;
            o.x = *(unsigned int*)&h01;
            o.y = *(unsigned int*)&h23;
            ((uint2*)xh)[i] = o;
        }
        return;
    }
    int bb = b - castblocks;
    for (int i = threadIdx.x; i < NBUCK; i += 256) lh[i] = 0;
    __syncthreads();
    int s0 = bb * SLAB, s1 = min(E, s0 + SLAB);
    for (int i = s0 + threadIdx.x; i < s1; i += 256)
        atomicAdd(&lh[dst[i] >> BSHIFT], 1);
    __syncthreads();
    for (int i = threadIdx.x; i < NBUCK; i += 256) gh[i * bpart + bb] = lh[i];
}

// ---------- exclusive-scan trio over gh (in-place) ----------
__global__ void scan1_kernel(int* __restrict__ gh, int* __restrict__ partial, int m) {
    __shared__ int s[256];
    int i = blockIdx.x * 256 + threadIdx.x;
    int v = (i < m) ? gh[i] : 0;
    s[threadIdx.x] = v;
    __syncthreads();
    for (int d = 1; d < 256; d <<= 1) {
        int t = (threadIdx.x >= d) ? s[threadIdx.x - d] : 0;
        __syncthreads();
        s[threadIdx.x] += t;
        __syncthreads();
    }
    int incl = s[threadIdx.x];
    if (i < m) gh[i] = incl - v;
    if (threadIdx.x == 255) partial[blockIdx.x] = incl;
}

__global__ void scan2_kernel(int* __restrict__ partial, int nb) {
    __shared__ int s[512];
    int t = threadIdx.x;
    int v = (t < nb) ? partial[t] : 0;
    s[t] = v;
    __syncthreads();
    for (int d = 1; d < 512; d <<= 1) {
        int u = (t >= d) ? s[t - d] : 0;
        __syncthreads();
        s[t] += u;
        __syncthreads();
    }
    if (t < nb) partial[t] = s[t] - v;
}

__global__ void scan3_kernel(int* __restrict__ gh, const int* __restrict__ partial, int m) {
    int i = blockIdx.x * 256 + threadIdx.x;
    if (i < m) gh[i] += partial[blockIdx.x];
}

// ---------- phase 2: LDS counting-sort slab by bucket, copy runs out ----------
__global__ __launch_bounds__(256) void phase2_kernel(const int* __restrict__ src,
                                                     const int* __restrict__ dst,
                                                     const int* __restrict__ gbase,
                                                     int2* __restrict__ pairs,
                                                     int E, int bpart) {
    __shared__ int lbase[NBUCK];
    __shared__ int lcur[NBUCK];
    __shared__ int lgb[NBUCK];
    __shared__ int sc[256];
    __shared__ int2 lp[SLAB];   // 32 KB
    int b = blockIdx.x;
    int t = threadIdx.x;
    for (int i = t; i < NBUCK; i += 256) lbase[i] = 0;
    __syncthreads();
    int s0 = b * SLAB, s1 = min(E, s0 + SLAB);
    for (int i = s0 + t; i < s1; i += 256)
        atomicAdd(&lbase[dst[i] >> BSHIFT], 1);
    __syncthreads();
    int v = (t < NBUCK) ? lbase[t] : 0;
    sc[t] = v;
    __syncthreads();
    for (int d = 1; d < 256; d <<= 1) {
        int u = (t >= d) ? sc[t - d] : 0;
        __syncthreads();
        sc[t] += u;
        __syncthreads();
    }
    if (t < NBUCK) {
        int excl = sc[t] - v;
        lbase[t] = excl;
        lcur[t] = excl;
        lgb[t] = gbase[t * bpart + b];
    }
    __syncthreads();
    for (int i = s0 + t; i < s1; i += 256) {
        int d = dst[i];
        int s = src[i];
        int bk = d >> BSHIFT;
        int pos = atomicAdd(&lcur[bk], 1);
        lp[pos] = make_int2(s, d);
    }
    __syncthreads();
    int m = s1 - s0;
    for (int i = t; i < m; i += 256) {
        int2 p = lp[i];
        int bk = p.y >> BSHIFT;
        pairs[lgb[bk] + (i - lbase[bk])] = p;
    }
}

// ---------- phase 3: per-bucket node hist (LDS) + scan -> cnt/offs + CSR finalize ----------
__global__ __launch_bounds__(512) void phase3_kernel(const int2* __restrict__ pairs,
                                                     const int* __restrict__ gbase,
                                                     int* __restrict__ cnt,
                                                     int* __restrict__ offs,
                                                     int* __restrict__ esrc,
                                                     int E, int bpart, int n) {
    __shared__ int lcnt[512];
    __shared__ int sc[512];
    __shared__ int lexcl[512];
    int g = blockIdx.x;
    int node0 = g << BSHIFT;
    int t = threadIdx.x;
    lcnt[t] = 0;
    __syncthreads();
    int S = gbase[g * bpart];
    int Eg = (g == NBUCK - 1) ? E : gbase[(g + 1) * bpart];
    // pass 1: count per node (LDS atomics)
    for (int i = S + t; i < Eg; i += 512)
        atomicAdd(&lcnt[pairs[i].y - node0], 1);
    __syncthreads();
    // exclusive scan of 512 counters
    int v = lcnt[t];
    sc[t] = v;
    __syncthreads();
    for (int d = 1; d < 512; d <<= 1) {
        int u = (t >= d) ? sc[t - d] : 0;
        __syncthreads();
        sc[t] += u;
        __syncthreads();
    }
    int excl = sc[t] - v;
    lexcl[t] = excl;
    int nd = node0 + t;
    if (nd < n) {
        cnt[nd] = v;
        offs[nd] = S + excl;
    }
    __syncthreads();
    // pass 2: place edges; lexcl doubles as cursor (old value = slot in bucket)
    for (int i = S + t; i < Eg; i += 512) {
        int2 p = pairs[i];
        int pos = atomicAdd(&lexcl[p.y - node0], 1);
        esrc[S + pos] = p.x;
    }
}

// ---------- aggregate: one 16-lane group per node (4 nodes/wave) ----------
// 16 lanes x 16B = one 256B feature row; NO cross-lane reduce, NO index shuffles.
// Main loop: 8 edges/iter = 8 dwordx4 in flight per group (up to 32 per wave).
// 4 independent fp16 accumulator chains per lane, combined in fp32 at the end.
#define ACC(c, r)                        \
    s[c][0] += *(half2v*)&(r).x;         \
    s[c][1] += *(half2v*)&(r).y;         \
    s[c][2] += *(half2v*)&(r).z;         \
    s[c][3] += *(half2v*)&(r).w;

__global__ void aggregate_kernel(const __half* __restrict__ feat, const int* __restrict__ esrc,
                                 const int* __restrict__ offs, const int* __restrict__ cnt,
                                 __half* __restrict__ agg, int n) {
    int wid = (blockIdx.x * blockDim.x + threadIdx.x) >> 6;
    int lane = threadIdx.x & 63;
    int grp = lane >> 4;            // 0..3: node slot within wave
    int l15 = lane & 15;
    int node = wid * 4 + grp;
    if (node >= n) return;
    int beg = offs[node];
    int deg = cnt[node];
    const _Float16* fbase = (const _Float16*)feat + l15 * 8;
    const int* ep = esrc + beg;

    half2v s[4][4];
#pragma unroll
    for (int c = 0; c < 4; c++)
#pragma unroll
        for (int k = 0; k < 4; k++) s[c][k] = (half2v)(_Float16)0;

    int j = 0;
    // 8 edges per iter: 8 independent dwordx4 loads in flight
    for (; j + 8 <= deg; j += 8) {
        int i0 = ep[j + 0], i1 = ep[j + 1], i2 = ep[j + 2], i3 = ep[j + 3];
        int i4 = ep[j + 4], i5 = ep[j + 5], i6 = ep[j + 6], i7 = ep[j + 7];
        uint4 r0 = *(const uint4*)(fbase + (size_t)i0 * DFEAT);
        uint4 r1 = *(const uint4*)(fbase + (size_t)i1 * DFEAT);
        uint4 r2 = *(const uint4*)(fbase + (size_t)i2 * DFEAT);
        uint4 r3 = *(const uint4*)(fbase + (size_t)i3 * DFEAT);
        uint4 r4 = *(const uint4*)(fbase + (size_t)i4 * DFEAT);
        uint4 r5 = *(const uint4*)(fbase + (size_t)i5 * DFEAT);
        uint4 r6 = *(const uint4*)(fbase + (size_t)i6 * DFEAT);
        uint4 r7 = *(const uint4*)(fbase + (size_t)i7 * DFEAT);
        ACC(0, r0) ACC(1, r1) ACC(2, r2) ACC(3, r3)
        ACC(0, r4) ACC(1, r5) ACC(2, r6) ACC(3, r7)
    }
    // 4 edges per iter
    for (; j + 4 <= deg; j += 4) {
        int i0 = ep[j + 0], i1 = ep[j + 1], i2 = ep[j + 2], i3 = ep[j + 3];
        uint4 r0 = *(const uint4*)(fbase + (size_t)i0 * DFEAT);
        uint4 r1 = *(const uint4*)(fbase + (size_t)i1 * DFEAT);
        uint4 r2 = *(const uint4*)(fbase + (size_t)i2 * DFEAT);
        uint4 r3 = *(const uint4*)(fbase + (size_t)i3 * DFEAT);
        ACC(0, r0) ACC(1, r1) ACC(2, r2) ACC(3, r3)
    }
    // tail: 1..3 edges, indices clamped in-range (duplicate loads are cache hits, zeroed)
    if (j < deg) {
        int rem = deg - j;
        int i0 = ep[j];
        int i1 = ep[j + (rem > 1 ? 1 : 0)];
        int i2 = ep[j + (rem > 2 ? 2 : 0)];
        uint4 r0 = *(const uint4*)(fbase + (size_t)i0 * DFEAT);
        uint4 r1 = *(const uint4*)(fbase + (size_t)i1 * DFEAT);
        uint4 r2 = *(const uint4*)(fbase + (size_t)i2 * DFEAT);
        if (rem < 2) { r1.x = 0u; r1.y = 0u; r1.z = 0u; r1.w = 0u; }
        if (rem < 3) { r2.x = 0u; r2.y = 0u; r2.z = 0u; r2.w = 0u; }
        ACC(0, r0) ACC(1, r1) ACC(2, r2)
    }

    // combine 4 chains in fp32; no cross-lane traffic at all
    float scale = 1.0f / fmaxf((float)deg, 1.0f);
    float a[8];
#pragma unroll
    for (int k = 0; k < 4; k++) {
        a[2 * k]     = ((float)s[0][k].x + (float)s[1][k].x) + ((float)s[2][k].x + (float)s[3][k].x);
        a[2 * k + 1] = ((float)s[0][k].y + (float)s[1][k].y) + ((float)s[2][k].y + (float)s[3][k].y);
    }
    __half2 h0 = __floats2half2_rn(a[0] * scale, a[1] * scale);
    __half2 h1 = __floats2half2_rn(a[2] * scale, a[3] * scale);
    __half2 h2 = __floats2half2_rn(a[4] * scale, a[5] * scale);
    __half2 h3 = __floats2half2_rn(a[6] * scale, a[7] * scale);
    uint4 o;
    o.x = *(unsigned int*)&h0;
    o.y = *(unsigned int*)&h1;
    o.z = *(unsigned int*)&h2;
    o.w = *(unsigned int*)&h3;
    *(uint4*)(agg + (size_t)node * DFEAT + l15 * 8) = o;
}

// ---------- MFMA dual-GEMM, LDS-staged weights, D[feat][node] orientation ----------
template <bool NORM_RELU>
__global__ __launch_bounds__(256) void gemm_mfma_kernel(
    const __half* __restrict__ A1_, const __half* __restrict__ A2_,
    const float* __restrict__ Wl, const float* __restrict__ Wr,
    const float* __restrict__ bias, float* __restrict__ out32,
    __half* __restrict__ out16, int n) {
    __shared__ __align__(16) _Float16 lw[128 * 136];   // 34.8 KB

    const _Float16* A1 = (const _Float16*)A1_;
    const _Float16* A2 = (const _Float16*)A2_;

    const int lane = threadIdx.x & 63;
    const int w = threadIdx.x >> 6;       // wave 0..3
    const int quad = lane >> 4;           // 0..3
    const int l15 = lane & 15;
    const int i0 = blockIdx.x * 128 + w * 32;   // wave's first node row

    floatx4 acc[2][8];
#pragma unroll
    for (int nt = 0; nt < 2; nt++)
#pragma unroll
        for (int ft = 0; ft < 8; ft++)
            acc[nt][ft] = (floatx4){0.f, 0.f, 0.f, 0.f};

    int r0 = i0 + l15;      if (r0 >= n) r0 = n - 1;
    int r1 = i0 + 16 + l15; if (r1 >= n) r1 = n - 1;
    const int kq = quad * 8;

    for (int half = 0; half < 2; half++) {
        const float* __restrict__ W = half ? Wr : Wl;
        const _Float16* __restrict__ A = half ? A2 : A1;
        if (half) __syncthreads();
        {
            int t = threadIdx.x;
            int row = t >> 1;
            int cb = (t & 1) * 64;
            const float4* sp = (const float4*)(W + row * DFEAT + cb);
            unsigned int* dp = (unsigned int*)&lw[row * 136 + cb];
#pragma unroll
            for (int q = 0; q < 16; q++) {
                float4 v = sp[q];
                __half2 h01 = __floats2half2_rn(v.x, v.y);
                __half2 h23 = __floats2half2_rn(v.z, v.w);
                dp[q * 2] = *(unsigned int*)&h01;
                dp[q * 2 + 1] = *(unsigned int*)&h23;
            }
        }
        __syncthreads();
#pragma unroll
        for (int kc = 0; kc < DFEAT; kc += 32) {
            half8 b0 = *(const half8*)(A + (size_t)r0 * DFEAT + kc + kq);
            half8 b1 = *(const half8*)(A + (size_t)r1 * DFEAT + kc + kq);
#pragma unroll
            for (int ft = 0; ft < 8; ft++) {
                half8 a = *(const half8*)&lw[(ft * 16 + l15) * 136 + kc + kq];
                acc[0][ft] = __builtin_amdgcn_mfma_f32_16x16x32_f16(a, b0, acc[0][ft], 0, 0, 0);
                acc[1][ft] = __builtin_amdgcn_mfma_f32_16x16x32_f16(a, b1, acc[1][ft], 0, 0, 0);
            }
        }
    }

#pragma unroll
    for (int nt = 0; nt < 2; nt++) {
        int node = i0 + nt * 16 + l15;
        float v[8][4];
#pragma unroll
        for (int ft = 0; ft < 8; ft++) {
            const float4 bq = *(const float4*)(bias + ft * 16 + quad * 4);
            v[ft][0] = acc[nt][ft][0] + bq.x;
            v[ft][1] = acc[nt][ft][1] + bq.y;
            v[ft][2] = acc[nt][ft][2] + bq.z;
            v[ft][3] = acc[nt][ft][3] + bq.w;
        }
        if (NORM_RELU) {
            float ss = 0.f;
#pragma unroll
            for (int ft = 0; ft < 8; ft++)
#pragma unroll
                for (int r = 0; r < 4; r++) ss = fmaf(v[ft][r], v[ft][r], ss);
            ss += __shfl_xor(ss, 16);
            ss += __shfl_xor(ss, 32);
            float inv = 1.0f / fmaxf(sqrtf(ss), 1e-12f);
#pragma unroll
            for (int ft = 0; ft < 8; ft++)
#pragma unroll
                for (int r = 0; r < 4; r++) v[ft][r] = fmaxf(v[ft][r] * inv, 0.0f);
        }
        if (node < n) {
            if (NORM_RELU) {
                __half* op = (__half*)out16 + (size_t)node * DFEAT + quad * 4;
#pragma unroll
                for (int ft = 0; ft < 8; ft++) {
                    __half2 h01 = __floats2half2_rn(v[ft][0], v[ft][1]);
                    __half2 h23 = __floats2half2_rn(v[ft][2], v[ft][3]);
                    uint2 o;
                    o.x = *(unsigned int*)&h01;
                    o.y = *(unsigned int*)&h23;
                    *(uint2*)(op + ft * 16) = o;
                }
            } else {
                float* op = out32 + (size_t)node * DFEAT + quad * 4;
#pragma unroll
                for (int ft = 0; ft < 8; ft++)
                    *(float4*)(op + ft * 16) = make_float4(v[ft][0], v[ft][1], v[ft][2], v[ft][3]);
            }
        }
    }
}

extern "C" void kernel_launch(void* const* d_in, const int* in_sizes, int n_in,
                              void* d_out, int out_size, void* d_ws, size_t ws_size,
                              hipStream_t stream) {
    const float* x = (const float*)d_in[0];
    const int* edge_index = (const int*)d_in[1];
    const float* W1l = (const float*)d_in[2];
    const float* b1 = (const float*)d_in[3];
    const float* W1r = (const float*)d_in[4];
    const float* W2l = (const float*)d_in[5];
    const float* b2 = (const float*)d_in[6];
    const float* W2r = (const float*)d_in[7];
    float* out = (float*)d_out;

    const int E = in_sizes[1] / 2;
    const int n = in_sizes[0] / DFEAT;  // 100000

    int* ws = (int*)d_ws;
    int* cnt = ws + WS_CNT;
    int* gh = ws + WS_GH;
    int* partialB = ws + WS_PARTB;
    int* offs = ws + WS_OFFS;
    int* esrc = ws + WS_ESRC;
    int2* pairs = (int2*)(ws + WS_AGGH);
    __half* aggh = (__half*)(ws + WS_AGGH);
    __half* casth = (__half*)(ws + WS_CASTH);

    const int* src = edge_index;
    const int* dst = edge_index + E;

    const int bpart = (E + SLAB - 1) / SLAB;        // 391
    const int m = NBUCK * bpart;                    // 76636
    const int blocksB = (m + 255) / 256;            // 300
    const int total4 = n * DFEAT / 4;
    const int castblocks = (total4 + 255) / 256;    // 12500

    prep_kernel<<<castblocks + bpart, 256, 0, stream>>>(x, casth, total4, dst, gh,
                                                        E, bpart, castblocks);
    scan1_kernel<<<blocksB, 256, 0, stream>>>(gh, partialB, m);
    scan2_kernel<<<1, 512, 0, stream>>>(partialB, blocksB);
    scan3_kernel<<<blocksB, 256, 0, stream>>>(gh, partialB, m);

    phase2_kernel<<<bpart, 256, 0, stream>>>(src, dst, gh, pairs, E, bpart);
    phase3_kernel<<<NBUCK, 512, 0, stream>>>(pairs, gh, cnt, offs, esrc, E, bpart, n);

    // 4 nodes per wave -> 16 waves per 256-thread block
    const int nwaves = (n + 3) / 4;
    const int aggb = (nwaves * 64 + 255) / 256;
    const int gemmb = (n + 127) / 128;

    // layer 1: agg(x_h) -> aggh; h = relu(normalize(aggh@W1l^T + b1 + x_h@W1r^T)) -> fp16 aggh
    aggregate_kernel<<<aggb, 256, 0, stream>>>(casth, esrc, offs, cnt, aggh, n);
    gemm_mfma_kernel<true><<<gemmb, 256, 0, stream>>>(aggh, casth, W1l, W1r, b1, nullptr, aggh, n);

    // layer 2: agg(h) -> casth; out = casth@W2l^T + b2 + h@W2r^T (fp32 to d_out)
    aggregate_kernel<<<aggb, 256, 0, stream>>>(aggh, esrc, offs, cnt, casth, n);
    gemm_mfma_kernel<false><<<gemmb, 256, 0, stream>>>(casth, aggh, W2l, W2r, b2, out, nullptr, n);
}